// Round 7
// baseline (433.918 us; speedup 1.0000x reference)
//
#include <hip/hip_runtime.h>
#include <hip/hip_bf16.h>
#include <math.h>

#define N_NODES 100000
#define N_EDGES 1600000
#define IN_FEATS 256
#define OUT_FEATS 64
#define NHEAD 4
#define F_TOT 256
#define ALPHA 0.2f

typedef __attribute__((ext_vector_type(8))) short short8;
typedef __attribute__((ext_vector_type(8))) unsigned short ush8;
typedef __attribute__((ext_vector_type(4))) float f32x4;

// ---------------- workspace layout (bytes) ----------------
#define OFF_HB    ((size_t)0)            // 51,200,000
#define OFF_HL    ((size_t)51200000)     // 1,600,000
#define OFF_HR    ((size_t)52800000)     // 1,600,000
#define OFF_CNT   ((size_t)54400000)     // 400,128
#define OFF_OFFS  ((size_t)54800128)     // 400,128
#define OFF_CUR   ((size_t)55200256)     // 400,128
#define OFF_CSORT ((size_t)55600384)     // 6,400,000
#define OFF_BSUM  ((size_t)62000384)     // 4,096
#define OFF_WT    ((size_t)62004480)     // 131,072

__device__ inline float bf2f(ushort u) { return __uint_as_float((uint)u << 16); }
__device__ inline ushort f2bf(float f) {
  __hip_bfloat16 b = __float2bfloat16(f);
  return *(ushort*)&b;
}

// ---------------- prep: W transpose/cast (blocks 0-15) + hist (blocks 16+) ----------------
#define PREP_CAST_BLKS 16
#define PREP_HIST_BLKS 512

__global__ __launch_bounds__(256) void prep_kernel(const float* __restrict__ W,
                                                   ushort* __restrict__ Wt,
                                                   const int* __restrict__ row,
                                                   int* __restrict__ counts, int E) {
  if (blockIdx.x < PREP_CAST_BLKS) {
    __shared__ float s[64][65];
    const int bi = blockIdx.x & 3;
    const int bj = blockIdx.x >> 2;
    const int tid = threadIdx.x;
    const int n0 = bi * 64, k0 = bj * 64;
    #pragma unroll
    for (int it = 0; it < 16; ++it) {
      int idx = it * 256 + tid;
      int r = idx >> 6, c = idx & 63;
      s[c][r] = W[(size_t)(k0 + r) * F_TOT + n0 + c];
    }
    __syncthreads();
    #pragma unroll
    for (int it = 0; it < 16; ++it) {
      int idx = it * 256 + tid;
      int nn = idx >> 6, kk = idx & 63;
      Wt[(size_t)(n0 + nn) * IN_FEATS + k0 + kk] = f2bf(s[nn][kk]);
    }
  } else {
    int gtid = (blockIdx.x - PREP_CAST_BLKS) * 256 + threadIdx.x;
    for (int i = gtid; i < E; i += PREP_HIST_BLKS * 256)
      atomicAdd(&counts[row[i]], 1);
  }
}

// ---------------- MFMA GEMM: BM=128, BN=256 (full N), 512 thr / 8 waves ----------------
#define GBM 128
#define GBK 64
#define NRBLK 782   // ceil(100000/128)

__global__ __launch_bounds__(512) void gemm_bf16(const float* __restrict__ X,
                                                 const ushort* __restrict__ Bt,  // Wt [256][256]
                                                 ushort* __restrict__ hb,
                                                 const float* __restrict__ a_l,
                                                 const float* __restrict__ a_r,
                                                 float* __restrict__ hl,
                                                 float* __restrict__ hr, int M) {
  __shared__ __align__(16) ushort As[GBM][GBK + 8];
  __shared__ __align__(16) ushort Bs[F_TOT][GBK + 8];
  const int row0 = blockIdx.x * GBM;
  const int tid = threadIdx.x;
  const int lane = tid & 63;
  const int wid = tid >> 6;
  const int wr = wid >> 2;
  const int wc = wid & 3;
  const int lr = lane & 15;
  const int kq = lane >> 4;

  f32x4 acc[4][4];
  #pragma unroll
  for (int i = 0; i < 4; ++i)
    #pragma unroll
    for (int j = 0; j < 4; ++j) acc[i][j] = (f32x4)(0.f);

  for (int k0 = 0; k0 < IN_FEATS; k0 += GBK) {
    {
      const int r = tid >> 2;
      const int sc = (tid & 3) * 16;
      const int gr = row0 + r;
      union { ushort u[16]; short8 s[2]; } t;
      if (gr < M) {
        const float* src = &X[(size_t)gr * IN_FEATS + k0 + sc];
        const float4 f0 = *(const float4*)(src);
        const float4 f1 = *(const float4*)(src + 4);
        const float4 f2 = *(const float4*)(src + 8);
        const float4 f3 = *(const float4*)(src + 12);
        t.u[0] = f2bf(f0.x);  t.u[1] = f2bf(f0.y);  t.u[2] = f2bf(f0.z);  t.u[3] = f2bf(f0.w);
        t.u[4] = f2bf(f1.x);  t.u[5] = f2bf(f1.y);  t.u[6] = f2bf(f1.z);  t.u[7] = f2bf(f1.w);
        t.u[8] = f2bf(f2.x);  t.u[9] = f2bf(f2.y);  t.u[10] = f2bf(f2.z); t.u[11] = f2bf(f2.w);
        t.u[12] = f2bf(f3.x); t.u[13] = f2bf(f3.y); t.u[14] = f2bf(f3.z); t.u[15] = f2bf(f3.w);
      } else {
        t.s[0] = (short8)(0); t.s[1] = (short8)(0);
      }
      __syncthreads();
      *(short8*)&As[r][sc] = t.s[0];
      *(short8*)&As[r][sc + 8] = t.s[1];
    }
    #pragma unroll
    for (int it = 0; it < 4; ++it) {
      int idx = it * 512 + tid;
      int r = idx >> 3, c8 = (idx & 7) * 8;
      *(short8*)&Bs[r][c8] = *(const short8*)&Bt[(size_t)r * IN_FEATS + k0 + c8];
    }
    __syncthreads();
    #pragma unroll
    for (int ks = 0; ks < 2; ++ks) {
      const int kb = ks * 32 + kq * 8;
      short8 af[4], bf[4];
      #pragma unroll
      for (int i = 0; i < 4; ++i) af[i] = *(const short8*)&As[wr * 64 + i * 16 + lr][kb];
      #pragma unroll
      for (int j = 0; j < 4; ++j) bf[j] = *(const short8*)&Bs[wc * 64 + j * 16 + lr][kb];
      #pragma unroll
      for (int i = 0; i < 4; ++i)
        #pragma unroll
        for (int j = 0; j < 4; ++j)
          acc[i][j] = __builtin_amdgcn_mfma_f32_16x16x32_bf16(af[i], bf[j], acc[i][j], 0, 0, 0);
    }
  }

  // epilogue 1: h bf16.  C mapping: col=lane&15, row=(lane>>4)*4+reg
  #pragma unroll
  for (int i = 0; i < 4; ++i) {
    int rbase = row0 + wr * 64 + i * 16 + kq * 4;
    #pragma unroll
    for (int j = 0; j < 4; ++j) {
      int cc = wc * 64 + j * 16 + lr;
      #pragma unroll
      for (int reg = 0; reg < 4; ++reg) {
        int r = rbase + reg;
        if (r < M) hb[(size_t)r * F_TOT + cc] = f2bf(acc[i][j][reg]);
      }
    }
  }

  // epilogue 2: hl/hr (wave's 64 cols == head wc)
  const int head = wc;
  float alv[4], arv[4];
  #pragma unroll
  for (int j = 0; j < 4; ++j) {
    alv[j] = a_l[head * OUT_FEATS + j * 16 + lr];
    arv[j] = a_r[head * OUT_FEATS + j * 16 + lr];
  }
  #pragma unroll
  for (int i = 0; i < 4; ++i) {
    #pragma unroll
    for (int reg = 0; reg < 4; ++reg) {
      float pl = 0.f, pr = 0.f;
      #pragma unroll
      for (int j = 0; j < 4; ++j) {
        pl = fmaf(acc[i][j][reg], alv[j], pl);
        pr = fmaf(acc[i][j][reg], arv[j], pr);
      }
      #pragma unroll
      for (int d = 8; d >= 1; d >>= 1) {
        pl += __shfl_xor(pl, d);
        pr += __shfl_xor(pr, d);
      }
      if (lr == 0) {
        int r = row0 + wr * 64 + i * 16 + kq * 4 + reg;
        if (r < M) {
          hl[r * NHEAD + head] = pl;
          hr[r * NHEAD + head] = pr;
        }
      }
    }
  }
}

// ---------------- CSR scan ----------------
__global__ __launch_bounds__(1024) void scan1_kernel(const int* __restrict__ counts,
                                                     int* __restrict__ offsets,
                                                     int* __restrict__ bsum, int n) {
  __shared__ int wsum[16];
  const int tid = threadIdx.x;
  const int lane = tid & 63;
  const int wid = tid >> 6;
  int i = blockIdx.x * 1024 + tid;
  int v = (i < n) ? counts[i] : 0;
  int inc = v;
  #pragma unroll
  for (int d = 1; d < 64; d <<= 1) {
    int t = __shfl_up(inc, d);
    if (lane >= d) inc += t;
  }
  if (lane == 63) wsum[wid] = inc;
  __syncthreads();
  if (tid < 16) {
    int x = wsum[tid];
    #pragma unroll
    for (int d = 1; d < 16; d <<= 1) {
      int t = __shfl_up(x, d);
      if (tid >= d) x += t;
    }
    wsum[tid] = x;
  }
  __syncthreads();
  int excl = ((wid > 0) ? wsum[wid - 1] : 0) + inc - v;
  if (i < n) offsets[i] = excl;
  if (tid == 0) bsum[blockIdx.x] = wsum[15];
}

// scan3 with scan2 folded in: every block re-scans the <=128 block sums locally
__global__ __launch_bounds__(256) void scan3_kernel(int* __restrict__ offsets,
                                                    int* __restrict__ cursor,
                                                    const int* __restrict__ bsum,
                                                    int n, int nblk) {
  __shared__ int sb[132];
  const int tid = threadIdx.x;
  if (tid < 64) {
    int run = 0;
    for (int base = 0; base < nblk; base += 64) {
      int idx = base + tid;
      int v = (idx < nblk) ? bsum[idx] : 0;
      int inc = v;
      #pragma unroll
      for (int d = 1; d < 64; d <<= 1) {
        int t = __shfl_up(inc, d);
        if (tid >= d) inc += t;
      }
      if (idx < nblk) sb[idx] = run + inc - v;
      run += __shfl(inc, 63);
    }
    if (tid == 0) sb[nblk] = run;
  }
  __syncthreads();
  int i = blockIdx.x * blockDim.x + tid;
  if (i < n) {
    int off = offsets[i] + sb[i >> 10];
    offsets[i] = off;
    cursor[i] = off;
  }
  if (i == 0) offsets[n] = sb[nblk];
}

// ---------------- scatter: col only ----------------
__global__ void scatter_kernel(const int* __restrict__ row, const int* __restrict__ col,
                               int* __restrict__ cursor, int* __restrict__ col_sorted, int E) {
  int i = blockIdx.x * blockDim.x + threadIdx.x;
  if (i < E) {
    int p = atomicAdd(&cursor[row[i]], 1);
    col_sorted[p] = col[i];
  }
}

// ---------------- aggregation: wave/node, inline exp from L2-resident hr, 8-deep MLP ----------------
__global__ __launch_bounds__(256) void agg_kernel(const ushort* __restrict__ hb,
                                                  const float* __restrict__ hl,
                                                  const float* __restrict__ hr,
                                                  const int* __restrict__ col_sorted,
                                                  const int* __restrict__ offsets,
                                                  float* __restrict__ out, int n) {
  int node = blockIdx.x * 4 + (threadIdx.x >> 6);
  int lane = threadIdx.x & 63;
  if (node >= n) return;
  const int s = offsets[node];
  const int t = offsets[node + 1];
  const int half = lane >> 5;       // which edge of the pair
  const int fl = lane & 31;         // feature-lane: features [fl*8, fl*8+8)
  const int head = fl >> 3;
  const float hln = hl[node * NHEAD + head];

  float denom = 0.f;
  float a[8] = {0.f, 0.f, 0.f, 0.f, 0.f, 0.f, 0.f, 0.f};
  const size_t fo = (size_t)fl * 8;

  auto edge = [&](int ii) {
    const int c = col_sorted[ii];
    const float g = hr[c * NHEAD + head];     // 1.6 MB table: L2-resident
    union { ush8 v; ushort u[8]; } hv;
    hv.v = *(const ush8*)&hb[(size_t)c * F_TOT + fo];
    float ee = hln + g;
    ee = ee > 0.f ? ee : ALPHA * ee;
    const float w = __expf(ee);               // no max-shift: |e| <~ 15 << 88
    denom += w;
    #pragma unroll
    for (int j = 0; j < 8; ++j) a[j] = fmaf(w, bf2f(hv.u[j]), a[j]);
  };

  int i = s + half;
  for (; i + 14 < t; i += 16) {
    edge(i);      edge(i + 2);  edge(i + 4);  edge(i + 6);
    edge(i + 8);  edge(i + 10); edge(i + 12); edge(i + 14);
  }
  for (; i < t; i += 2) edge(i);

  // cross-half reduce (lanes l and l^32 share fl)
  denom += __shfl_xor(denom, 32);
  #pragma unroll
  for (int j = 0; j < 8; ++j) a[j] += __shfl_xor(a[j], 32);

  const float inv = 1.f / (denom + 1e-16f);
  float4 o = make_float4(a[half * 4 + 0] * inv, a[half * 4 + 1] * inv,
                         a[half * 4 + 2] * inv, a[half * 4 + 3] * inv);
  *(float4*)&out[(size_t)node * F_TOT + fl * 8 + half * 4] = o;
}

// ---------------- launcher ----------------
extern "C" void kernel_launch(void* const* d_in, const int* in_sizes, int n_in,
                              void* d_out, int out_size, void* d_ws, size_t ws_size,
                              hipStream_t stream) {
  const float* x   = (const float*)d_in[0];
  const float* W   = (const float*)d_in[1];
  const float* a_l = (const float*)d_in[2];
  const float* a_r = (const float*)d_in[3];
  const int*   row = (const int*)d_in[4];
  const int*   col = (const int*)d_in[5];
  float* out = (float*)d_out;

  int n = in_sizes[0] / IN_FEATS;   // 100000
  int E = in_sizes[4];              // 1600000

  char* ws = (char*)d_ws;
  ushort* hb      = (ushort*)(ws + OFF_HB);
  float*  hl      = (float*)(ws + OFF_HL);
  float*  hr      = (float*)(ws + OFF_HR);
  int* counts     = (int*)(ws + OFF_CNT);
  int* offsets    = (int*)(ws + OFF_OFFS);
  int* cursor     = (int*)(ws + OFF_CUR);
  int* col_sorted = (int*)(ws + OFF_CSORT);
  int* bsum       = (int*)(ws + OFF_BSUM);
  ushort* Wt      = (ushort*)(ws + OFF_WT);

  // 1. zero counts
  hipMemsetAsync(counts, 0, (size_t)(n + 1) * sizeof(int), stream);
  // 2. prep: W transpose/cast + histogram
  prep_kernel<<<PREP_CAST_BLKS + PREP_HIST_BLKS, 256, 0, stream>>>(W, Wt, row, counts, E);
  // 3. GEMM (x read once) + fused hl/hr epilogue
  gemm_bf16<<<NRBLK, 512, 0, stream>>>(x, Wt, hb, a_l, a_r, hl, hr, n);
  // 4. CSR scan (scan2 folded into scan3)
  int nblk = (n + 1023) / 1024;  // 98
  scan1_kernel<<<nblk, 1024, 0, stream>>>(counts, offsets, bsum, n);
  scan3_kernel<<<(n + 255) / 256, 256, 0, stream>>>(offsets, cursor, bsum, n, nblk);
  // 5. scatter (col only, full-width)
  scatter_kernel<<<(E + 255) / 256, 256, 0, stream>>>(row, col, cursor, col_sorted, E);
  // 6. aggregation (inline softmax weights, pure gather + FMA)
  agg_kernel<<<(n + 3) / 4, 256, 0, stream>>>(hb, hl, hr, col_sorted, offsets, out, n);
}

// Round 8
// 386.959 us; speedup vs baseline: 1.1214x; 1.1214x over previous
//
#include <hip/hip_runtime.h>
#include <hip/hip_bf16.h>
#include <math.h>

#define N_NODES 100000
#define N_EDGES 1600000
#define IN_FEATS 256
#define OUT_FEATS 64
#define NHEAD 4
#define F_TOT 256
#define ALPHA 0.2f

typedef __attribute__((ext_vector_type(8))) short short8;
typedef __attribute__((ext_vector_type(8))) unsigned short ush8;
typedef __attribute__((ext_vector_type(4))) float f32x4;

// ---------------- workspace layout (bytes) ----------------
#define OFF_HB    ((size_t)0)            // 51,200,000
#define OFF_HL    ((size_t)51200000)     // 1,600,000
#define OFF_HR    ((size_t)52800000)     // 1,600,000
#define OFF_CNT   ((size_t)54400000)     // 400,128
#define OFF_OFFS  ((size_t)54800128)     // 400,128
#define OFF_CUR   ((size_t)55200256)     // 400,128
#define OFF_CSORT ((size_t)55600384)     // 6,400,000
#define OFF_ESORT ((size_t)62000384)     // 25,600,000 (E * 16B)
#define OFF_BSUM  ((size_t)87600384)     // 4,096
#define OFF_WT    ((size_t)87604480)     // 131,072
// total ~87.7 MB

__device__ inline float bf2f(ushort u) { return __uint_as_float((uint)u << 16); }
__device__ inline ushort f2bf(float f) {
  __hip_bfloat16 b = __float2bfloat16(f);
  return *(ushort*)&b;
}

// ---------------- prep: W transpose/cast (blocks 0-15) + hist (blocks 16+) ----------------
#define PREP_CAST_BLKS 16
#define PREP_HIST_BLKS 512

__global__ __launch_bounds__(256) void prep_kernel(const float* __restrict__ W,
                                                   ushort* __restrict__ Wt,
                                                   const int* __restrict__ row,
                                                   int* __restrict__ counts, int E) {
  if (blockIdx.x < PREP_CAST_BLKS) {
    __shared__ float s[64][65];
    const int bi = blockIdx.x & 3;
    const int bj = blockIdx.x >> 2;
    const int tid = threadIdx.x;
    const int n0 = bi * 64, k0 = bj * 64;
    #pragma unroll
    for (int it = 0; it < 16; ++it) {
      int idx = it * 256 + tid;
      int r = idx >> 6, c = idx & 63;
      s[c][r] = W[(size_t)(k0 + r) * F_TOT + n0 + c];
    }
    __syncthreads();
    #pragma unroll
    for (int it = 0; it < 16; ++it) {
      int idx = it * 256 + tid;
      int nn = idx >> 6, kk = idx & 63;
      Wt[(size_t)(n0 + nn) * IN_FEATS + k0 + kk] = f2bf(s[nn][kk]);
    }
  } else {
    int gtid = (blockIdx.x - PREP_CAST_BLKS) * 256 + threadIdx.x;
    for (int i = gtid; i < E; i += PREP_HIST_BLKS * 256)
      atomicAdd(&counts[row[i]], 1);
  }
}

// ---------------- MFMA GEMM: BM=128, BN=256 (full N), GBK=32 (30 KB LDS -> 5 blk/CU) ----------------
#define GBM 128
#define GBK 32
#define NRBLK 782   // ceil(100000/128)

__global__ __launch_bounds__(512) void gemm_bf16(const float* __restrict__ X,
                                                 const ushort* __restrict__ Bt,  // Wt [256][256]
                                                 ushort* __restrict__ hb,
                                                 const float* __restrict__ a_l,
                                                 const float* __restrict__ a_r,
                                                 float* __restrict__ hl,
                                                 float* __restrict__ hr, int M) {
  __shared__ __align__(16) ushort As[GBM][GBK + 8];   // 128*40*2 = 10,240 B
  __shared__ __align__(16) ushort Bs[F_TOT][GBK + 8]; // 256*40*2 = 20,480 B
  const int row0 = blockIdx.x * GBM;
  const int tid = threadIdx.x;
  const int lane = tid & 63;
  const int wid = tid >> 6;
  const int wr = wid >> 2;         // 0..1  row half
  const int wc = wid & 3;          // 0..3  col quarter == head
  const int lr = lane & 15;
  const int kq = lane >> 4;

  f32x4 acc[4][4];
  #pragma unroll
  for (int i = 0; i < 4; ++i)
    #pragma unroll
    for (int j = 0; j < 4; ++j) acc[i][j] = (f32x4)(0.f);

  for (int k0 = 0; k0 < IN_FEATS; k0 += GBK) {
    // prefetch A: 128 rows x 32 k f32 -> 8 floats/thread
    const int ra = tid >> 2;            // 0..127
    const int sca = (tid & 3) * 8;      // 0,8,16,24
    const int gra = row0 + ra;
    union { ushort u[8]; short8 s; } ta;
    if (gra < M) {
      const float* src = &X[(size_t)gra * IN_FEATS + k0 + sca];
      const float4 f0 = *(const float4*)(src);
      const float4 f1 = *(const float4*)(src + 4);
      ta.u[0] = f2bf(f0.x); ta.u[1] = f2bf(f0.y); ta.u[2] = f2bf(f0.z); ta.u[3] = f2bf(f0.w);
      ta.u[4] = f2bf(f1.x); ta.u[5] = f2bf(f1.y); ta.u[6] = f2bf(f1.z); ta.u[7] = f2bf(f1.w);
    } else {
      ta.s = (short8)(0);
    }
    // prefetch B: 256 rows x 32 k bf16 = 1024 short8 -> 2/thread
    short8 tb[2];
    #pragma unroll
    for (int it = 0; it < 2; ++it) {
      int idx = it * 512 + tid;
      int r = idx >> 2, c8 = (idx & 3) * 8;
      tb[it] = *(const short8*)&Bt[(size_t)r * IN_FEATS + k0 + c8];
    }
    __syncthreads();   // protect LDS from previous iteration's readers
    *(short8*)&As[ra][sca] = ta.s;
    #pragma unroll
    for (int it = 0; it < 2; ++it) {
      int idx = it * 512 + tid;
      int r = idx >> 2, c8 = (idx & 3) * 8;
      *(short8*)&Bs[r][c8] = tb[it];
    }
    __syncthreads();
    const int kb = kq * 8;
    short8 af[4], bf[4];
    #pragma unroll
    for (int i = 0; i < 4; ++i) af[i] = *(const short8*)&As[wr * 64 + i * 16 + lr][kb];
    #pragma unroll
    for (int j = 0; j < 4; ++j) bf[j] = *(const short8*)&Bs[wc * 64 + j * 16 + lr][kb];
    #pragma unroll
    for (int i = 0; i < 4; ++i)
      #pragma unroll
      for (int j = 0; j < 4; ++j)
        acc[i][j] = __builtin_amdgcn_mfma_f32_16x16x32_bf16(af[i], bf[j], acc[i][j], 0, 0, 0);
  }

  // epilogue 1: h bf16.  C mapping: col=lane&15, row=(lane>>4)*4+reg
  #pragma unroll
  for (int i = 0; i < 4; ++i) {
    int rbase = row0 + wr * 64 + i * 16 + kq * 4;
    #pragma unroll
    for (int j = 0; j < 4; ++j) {
      int cc = wc * 64 + j * 16 + lr;
      #pragma unroll
      for (int reg = 0; reg < 4; ++reg) {
        int r = rbase + reg;
        if (r < M) hb[(size_t)r * F_TOT + cc] = f2bf(acc[i][j][reg]);
      }
    }
  }

  // epilogue 2: hl/hr (wave's 64 cols == head wc)
  const int head = wc;
  float alv[4], arv[4];
  #pragma unroll
  for (int j = 0; j < 4; ++j) {
    alv[j] = a_l[head * OUT_FEATS + j * 16 + lr];
    arv[j] = a_r[head * OUT_FEATS + j * 16 + lr];
  }
  #pragma unroll
  for (int i = 0; i < 4; ++i) {
    #pragma unroll
    for (int reg = 0; reg < 4; ++reg) {
      float pl = 0.f, pr = 0.f;
      #pragma unroll
      for (int j = 0; j < 4; ++j) {
        pl = fmaf(acc[i][j][reg], alv[j], pl);
        pr = fmaf(acc[i][j][reg], arv[j], pr);
      }
      #pragma unroll
      for (int d = 8; d >= 1; d >>= 1) {
        pl += __shfl_xor(pl, d);
        pr += __shfl_xor(pr, d);
      }
      if (lr == 0) {
        int r = row0 + wr * 64 + i * 16 + kq * 4 + reg;
        if (r < M) {
          hl[r * NHEAD + head] = pl;
          hr[r * NHEAD + head] = pr;
        }
      }
    }
  }
}

// ---------------- CSR scan ----------------
__global__ __launch_bounds__(1024) void scan1_kernel(const int* __restrict__ counts,
                                                     int* __restrict__ offsets,
                                                     int* __restrict__ bsum, int n) {
  __shared__ int wsum[16];
  const int tid = threadIdx.x;
  const int lane = tid & 63;
  const int wid = tid >> 6;
  int i = blockIdx.x * 1024 + tid;
  int v = (i < n) ? counts[i] : 0;
  int inc = v;
  #pragma unroll
  for (int d = 1; d < 64; d <<= 1) {
    int t = __shfl_up(inc, d);
    if (lane >= d) inc += t;
  }
  if (lane == 63) wsum[wid] = inc;
  __syncthreads();
  if (tid < 16) {
    int x = wsum[tid];
    #pragma unroll
    for (int d = 1; d < 16; d <<= 1) {
      int t = __shfl_up(x, d);
      if (tid >= d) x += t;
    }
    wsum[tid] = x;
  }
  __syncthreads();
  int excl = ((wid > 0) ? wsum[wid - 1] : 0) + inc - v;
  if (i < n) offsets[i] = excl;
  if (tid == 0) bsum[blockIdx.x] = wsum[15];
}

// scan3 with scan2 folded in: every block re-scans the <=128 block sums locally
__global__ __launch_bounds__(256) void scan3_kernel(int* __restrict__ offsets,
                                                    int* __restrict__ cursor,
                                                    const int* __restrict__ bsum,
                                                    int n, int nblk) {
  __shared__ int sb[132];
  const int tid = threadIdx.x;
  if (tid < 64) {
    int run = 0;
    for (int base = 0; base < nblk; base += 64) {
      int idx = base + tid;
      int v = (idx < nblk) ? bsum[idx] : 0;
      int inc = v;
      #pragma unroll
      for (int d = 1; d < 64; d <<= 1) {
        int t = __shfl_up(inc, d);
        if (tid >= d) inc += t;
      }
      if (idx < nblk) sb[idx] = run + inc - v;
      run += __shfl(inc, 63);
    }
    if (tid == 0) sb[nblk] = run;
  }
  __syncthreads();
  int i = blockIdx.x * blockDim.x + tid;
  if (i < n) {
    int off = offsets[i] + sb[i >> 10];
    offsets[i] = off;
    cursor[i] = off;
  }
  if (i == 0) offsets[n] = sb[nblk];
}

// ---------------- scatter + per-edge exp weights (no max: scores are O(10) << 88) ----------------
__global__ void scatter_esort(const int* __restrict__ row, const int* __restrict__ col,
                              const float* __restrict__ hl, const float* __restrict__ hr,
                              int* __restrict__ cursor, int* __restrict__ col_sorted,
                              float* __restrict__ esort, int E) {
  int i = blockIdx.x * blockDim.x + threadIdx.x;
  if (i >= E) return;
  const int r = row[i];
  const int c = col[i];
  const float4 l4 = *(const float4*)&hl[r * NHEAD];
  const float4 r4 = *(const float4*)&hr[c * NHEAD];
  float e0 = l4.x + r4.x, e1 = l4.y + r4.y, e2 = l4.z + r4.z, e3 = l4.w + r4.w;
  e0 = e0 > 0.f ? e0 : ALPHA * e0;
  e1 = e1 > 0.f ? e1 : ALPHA * e1;
  e2 = e2 > 0.f ? e2 : ALPHA * e2;
  e3 = e3 > 0.f ? e3 : ALPHA * e3;
  float4 w = make_float4(__expf(e0), __expf(e1), __expf(e2), __expf(e3));
  int p = atomicAdd(&cursor[r], 1);
  col_sorted[p] = c;
  *(float4*)&esort[(size_t)p * 4] = w;
}

// ---------------- aggregation: wave/node, sequential weight stream, 4-wide MLP ----------------
__global__ __launch_bounds__(256) void agg_kernel(const ushort* __restrict__ hb,
                                                  const int* __restrict__ col_sorted,
                                                  const float* __restrict__ esort,
                                                  const int* __restrict__ offsets,
                                                  float* __restrict__ out, int n) {
  int node = blockIdx.x * 4 + (threadIdx.x >> 6);
  int lane = threadIdx.x & 63;
  if (node >= n) return;
  const int s = offsets[node];
  const int t = offsets[node + 1];
  const int half = lane >> 5;       // which edge of the pair
  const int fl = lane & 31;         // feature-lane: features [fl*8, fl*8+8)
  const int head = fl >> 3;

  float denom = 0.f;
  float a[8] = {0.f, 0.f, 0.f, 0.f, 0.f, 0.f, 0.f, 0.f};
  const size_t fo = (size_t)fl * 8;

  auto edge = [&](int ii) {
    const int c = col_sorted[ii];
    const float w = esort[(size_t)ii * 4 + head];
    union { ush8 v; ushort u[8]; } hv;
    hv.v = *(const ush8*)&hb[(size_t)c * F_TOT + fo];
    denom += w;
    #pragma unroll
    for (int j = 0; j < 8; ++j) a[j] = fmaf(w, bf2f(hv.u[j]), a[j]);
  };

  int i = s + half;
  for (; i + 6 < t; i += 8) { edge(i); edge(i + 2); edge(i + 4); edge(i + 6); }
  for (; i < t; i += 2) edge(i);

  // cross-half reduce (lanes l and l^32 share fl)
  denom += __shfl_xor(denom, 32);
  #pragma unroll
  for (int j = 0; j < 8; ++j) a[j] += __shfl_xor(a[j], 32);

  const float inv = 1.f / (denom + 1e-16f);
  float4 o = make_float4(a[half * 4 + 0] * inv, a[half * 4 + 1] * inv,
                         a[half * 4 + 2] * inv, a[half * 4 + 3] * inv);
  *(float4*)&out[(size_t)node * F_TOT + fl * 8 + half * 4] = o;
}

// ---------------- launcher ----------------
extern "C" void kernel_launch(void* const* d_in, const int* in_sizes, int n_in,
                              void* d_out, int out_size, void* d_ws, size_t ws_size,
                              hipStream_t stream) {
  const float* x   = (const float*)d_in[0];
  const float* W   = (const float*)d_in[1];
  const float* a_l = (const float*)d_in[2];
  const float* a_r = (const float*)d_in[3];
  const int*   row = (const int*)d_in[4];
  const int*   col = (const int*)d_in[5];
  float* out = (float*)d_out;

  int n = in_sizes[0] / IN_FEATS;   // 100000
  int E = in_sizes[4];              // 1600000

  char* ws = (char*)d_ws;
  ushort* hb      = (ushort*)(ws + OFF_HB);
  float*  hl      = (float*)(ws + OFF_HL);
  float*  hr      = (float*)(ws + OFF_HR);
  int* counts     = (int*)(ws + OFF_CNT);
  int* offsets    = (int*)(ws + OFF_OFFS);
  int* cursor     = (int*)(ws + OFF_CUR);
  int* col_sorted = (int*)(ws + OFF_CSORT);
  float* esort    = (float*)(ws + OFF_ESORT);
  int* bsum       = (int*)(ws + OFF_BSUM);
  ushort* Wt      = (ushort*)(ws + OFF_WT);

  // 1. zero counts
  hipMemsetAsync(counts, 0, (size_t)(n + 1) * sizeof(int), stream);
  // 2. prep: W transpose/cast + histogram
  prep_kernel<<<PREP_CAST_BLKS + PREP_HIST_BLKS, 256, 0, stream>>>(W, Wt, row, counts, E);
  // 3. GEMM (x read once; 30 KB LDS -> 5 blocks/CU) + fused hl/hr epilogue
  gemm_bf16<<<NRBLK, 512, 0, stream>>>(x, Wt, hb, a_l, a_r, hl, hr, n);
  // 4. CSR scan (scan2 folded into scan3)
  int nblk = (n + 1023) / 1024;  // 98
  scan1_kernel<<<nblk, 1024, 0, stream>>>(counts, offsets, bsum, n);
  scan3_kernel<<<(n + 255) / 256, 256, 0, stream>>>(offsets, cursor, bsum, n, nblk);
  // 5. scatter + per-edge exp weights
  scatter_esort<<<(E + 255) / 256, 256, 0, stream>>>(row, col, hl, hr, cursor,
                                                     col_sorted, esort, E);
  // 6. aggregation (pure gather + FMA)
  agg_kernel<<<(n + 3) / 4, 256, 0, stream>>>(hb, col_sorted, esort, offsets, out, n);
}